// Round 1
// baseline (1357.141 us; speedup 1.0000x reference)
//
#include <hip/hip_runtime.h>

// x (P,B,C,H,W)=(8,4,32,256,256) fp32; w* (C,C,P,M1,M2)=(32,32,8,32,32)
// Kept modes: ky in [0,32) u [224,256)  (s=0..63, ky = s<32 ? s : s+192), kx in [0,32)

constexpr float TWO_PI = 6.28318530717958647692f;

// ---------------- Kernel 1: forward truncated DFT per plane ----------------
// Single-pass restructure (both kx halves at once):
//   Chunk-pair c (c<16): rows h = c*8+r and h+128 (r<8) are loaded and
//   w-parity-folded into u[par][row16][w00*8+w1]  (w0 = 16*w1 + w00).
//   Stage A: thread (row16, kxh) computes X1[row][kx] for BOTH kx=kxh and
//   kxh+16: Bt[w1]=e^{-2pi i w1 kxh/16} and the u-parity are identical for
//   the pair, so the 8-term inner sums (Sx,Sy) are shared; only the A[w00]
//   twiddles differ (LDS table At, conflict-free).
//   Stage B: thread (sg, kx) holds 8 output modes s=sg+8j (constant parity)
//   in registers and accumulates per chunk from buf, folding h-parity on
//   the fly.  No full X1 tile in LDS.  2 barriers/chunk.
//   Global loads for c+1 issued before stage A, written to LDS after stage B.
__global__ __launch_bounds__(256, 4) void fwd_dft(const float* __restrict__ x,
                                                  float2* __restrict__ X2) {
  __shared__ float2 tw[256];                       // e^{+2pi i t/256}
  __shared__ float2 At[512];                       // [w00][kx]: e^{-2pi i w00 kx/256}
  __shared__ __align__(16) float u[2 * 16 * 132];  // [par][row16][w00*8+w1]
  __shared__ float2 buf[16 * 33];                  // X1 chunk [row16][kx], stride 33

  const int t = threadIdx.x;
  {
    float a = (float)t * (TWO_PI / 256.f);
    tw[t] = make_float2(cosf(a), sinf(a));
  }
#pragma unroll
  for (int i = 0; i < 2; ++i) {
    int idx = t + 256 * i;
    int w00 = idx >> 5, kx = idx & 31;
    float a = (TWO_PI / 256.f) * (float)(w00 * kx);
    At[idx] = make_float2(cosf(a), -sinf(a));
  }

  // stage A role
  const int rowA = t >> 4, kxh = t & 15, par = kxh & 1;
  float2 Bt[8];
#pragma unroll
  for (int w1 = 0; w1 < 8; ++w1) {
    float a = (TWO_PI / 16.f) * (float)(w1 * kxh);
    Bt[w1] = make_float2(cosf(a), -sinf(a));
  }
  // loader role
  const int lrow = t >> 5, w4 = t & 31;
  const float4* x4 = (const float4*)(x + (size_t)blockIdx.x * 65536);
  // stage B role (kxb == w4, sg == lrow; kept separate for clarity)
  const int sg = t >> 5, kxb = t & 31;
  const float sgn = (sg & 1) ? -1.f : 1.f;
  float2 acc[8];
#pragma unroll
  for (int j = 0; j < 8; ++j) acc[j] = make_float2(0.f, 0.f);

  float* const U0 = u;
  float* const U1 = u + 2112;
  const int ibase = lrow * 132 + 32 * (w4 & 3) + (w4 >> 2);
  const float* const up = u + par * 2112 + rowA * 132;

  float4 pa0, pb0, pa1, pb1;

#define LOADC(c)                        \
  {                                     \
    int h = (c) * 8 + lrow;             \
    pa0 = x4[h * 64 + w4];              \
    pb0 = x4[h * 64 + w4 + 32];         \
    pa1 = x4[(h + 128) * 64 + w4];      \
    pb1 = x4[(h + 128) * 64 + w4 + 32]; \
  }
#define STOREU()                                                      \
  {                                                                   \
    U0[ibase] = pa0.x + pb0.x;      U1[ibase] = pa0.x - pb0.x;        \
    U0[ibase + 8] = pa0.y + pb0.y;  U1[ibase + 8] = pa0.y - pb0.y;    \
    U0[ibase + 16] = pa0.z + pb0.z; U1[ibase + 16] = pa0.z - pb0.z;   \
    U0[ibase + 24] = pa0.w + pb0.w; U1[ibase + 24] = pa0.w - pb0.w;   \
    const int i1 = ibase + 1056;                                      \
    U0[i1] = pa1.x + pb1.x;      U1[i1] = pa1.x - pb1.x;              \
    U0[i1 + 8] = pa1.y + pb1.y;  U1[i1 + 8] = pa1.y - pb1.y;          \
    U0[i1 + 16] = pa1.z + pb1.z; U1[i1 + 16] = pa1.z - pb1.z;         \
    U0[i1 + 24] = pa1.w + pb1.w; U1[i1 + 24] = pa1.w - pb1.w;         \
  }

  LOADC(0);
  STOREU();
  __syncthreads();

  for (int c = 0; c < 16; ++c) {
    if (c < 15) LOADC(c + 1);  // issue early; consumed by STOREU after stage B
    // ---- stage A: X1 for 16 rows x 32 kx of this chunk-pair ----
    float ax1 = 0.f, ay1 = 0.f, ax2 = 0.f, ay2 = 0.f;
#pragma unroll
    for (int w00 = 0; w00 < 16; ++w00) {
      float4 q0 = *(const float4*)(up + w00 * 8);
      float4 q1 = *(const float4*)(up + w00 * 8 + 4);
      float Sx = q0.x + q0.y * Bt[1].x + q0.z * Bt[2].x + q0.w * Bt[3].x +
                 q1.x * Bt[4].x + q1.y * Bt[5].x + q1.z * Bt[6].x +
                 q1.w * Bt[7].x;
      float Sy = q0.y * Bt[1].y + q0.z * Bt[2].y + q0.w * Bt[3].y +
                 q1.x * Bt[4].y + q1.y * Bt[5].y + q1.z * Bt[6].y +
                 q1.w * Bt[7].y;
      float2 A1 = At[w00 * 32 + kxh];
      float2 A2 = At[w00 * 32 + kxh + 16];
      ax1 += A1.x * Sx - A1.y * Sy;
      ay1 += A1.x * Sy + A1.y * Sx;
      ax2 += A2.x * Sx - A2.y * Sy;
      ay2 += A2.x * Sy + A2.y * Sx;
    }
    buf[rowA * 33 + kxh] = make_float2(ax1, ay1);
    buf[rowA * 33 + kxh + 16] = make_float2(ax2, ay2);
    __syncthreads();
    // ---- stage B: fold h-parity, accumulate 8 modes per thread ----
#pragma unroll
    for (int r = 0; r < 8; ++r) {
      const int h0 = c * 8 + r;
      float2 a = buf[r * 33 + kxb];
      float2 b = buf[(r + 8) * 33 + kxb];
      float vx = fmaf(sgn, b.x, a.x);
      float vy = fmaf(sgn, b.y, a.y);
      int tix = h0 * sg;        // (h0*ky_j)&255 walked incrementally
      const int h8 = h0 << 3;
#pragma unroll
      for (int j = 0; j < 8; ++j) {
        float2 z = tw[tix & 255];
        // acc += v * conj(z)
        acc[j].x += vx * z.x + vy * z.y;
        acc[j].y += vy * z.x - vx * z.y;
        tix += h8;
        if (j == 3) tix += (h0 << 7) + (h0 << 6);  // jump ky by +192 at s>=32
      }
    }
    if (c < 15) STOREU();
    __syncthreads();
  }
#undef LOADC
#undef STOREU

  float2* X2p = X2 + (size_t)blockIdx.x * 2048;
#pragma unroll
  for (int j = 0; j < 8; ++j) X2p[(sg + 8 * j) * 32 + kxb] = acc[j];
}

// ---------------- Kernel 2: channel mixing (unchanged) ----------------
__global__ __launch_bounds__(256) void mix(const float2* __restrict__ X2,
                                           const float* __restrict__ w1re,
                                           const float* __restrict__ w1im,
                                           const float* __restrict__ w4re,
                                           const float* __restrict__ w4im,
                                           float2* __restrict__ Y2) {
  const int n = blockIdx.x * 256 + threadIdx.x;
  const int kx = n & 31;
  const int s = (n >> 5) & 63;
  const int o = (n >> 11) & 31;
  const int p = n >> 16;
  const float* wre;
  const float* wim;
  int y;
  if (s < 32) { wre = w1re; wim = w1im; y = s; }
  else        { wre = w4re; wim = w4im; y = s - 32; }
  const size_t wbase = (size_t)o * 8192 + (size_t)p * 1024 + y * 32 + kx;
  const size_t in_base = ((size_t)p * 4 * 32) * 2048 + s * 32 + kx;
  float2 acc[4] = {make_float2(0.f, 0.f), make_float2(0.f, 0.f),
                   make_float2(0.f, 0.f), make_float2(0.f, 0.f)};
#pragma unroll 4
  for (int i = 0; i < 32; ++i) {
    const float wr = wre[wbase + (size_t)i * 262144];
    const float wi = wim[wbase + (size_t)i * 262144];
#pragma unroll
    for (int b = 0; b < 4; ++b) {
      float2 v = X2[in_base + (size_t)b * 65536 + (size_t)i * 2048];
      acc[b].x += v.x * wr - v.y * wi;
      acc[b].y += v.x * wi + v.y * wr;
    }
  }
  const size_t out_base = ((size_t)p * 4 * 32 + o) * 2048 + s * 32 + kx;
#pragma unroll
  for (int b = 0; b < 4; ++b) Y2[out_base + (size_t)b * 65536] = acc[b];
}

// ---------------- Kernel 3: inverse truncated DFT per plane ----------------
__global__ __launch_bounds__(256) void inv_dft(const float2* __restrict__ Y2,
                                               float* __restrict__ out) {
  __shared__ float2 tw[256];
  __shared__ float2 Ys[64 * 32];       // input modes [s][kx]
  __shared__ float2 Y1c[4 * 32 * 32];  // [q][hh][k] compact quad rows
  const int t = threadIdx.x;
  {
    float a = (float)t * (TWO_PI / 256.f);
    tw[t] = make_float2(cosf(a), sinf(a));
  }
  {
    const float4* src = (const float4*)(Y2 + (size_t)blockIdx.x * 2048);
    float4* dst = (float4*)Ys;
#pragma unroll
    for (int q = 0; q < 4; ++q) dst[t + 256 * q] = src[t + 256 * q];
  }
  const int lane = t & 63, wv = t >> 6;
  const int kx = lane & 31, hg = lane >> 5;
  const float scale = (kx == 0) ? (1.f / 65536.f) : (2.f / 65536.f);
  // Stage E register twiddles: T[k] = e^{+2pi i lane*k/256}
  float2 T[32];
#pragma unroll
  for (int k = 0; k < 32; ++k) {
    float a = (TWO_PI / 256.f) * (float)(lane * k);
    T[k] = make_float2(cosf(a), sinf(a));
  }
  __syncthreads();
  float* op = out + (size_t)blockIdx.x * 65536;

  for (int pass = 0; pass < 2; ++pass) {
    const int h0base = pass * 32;
    // ---- Stage D ----
    for (int iter = 0; iter < 4; ++iter) {
      const int h0 = h0base + wv * 8 + iter * 2 + hg;
      float B0x = 0, B0y = 0, B1x = 0, B1y = 0;
      float B2x = 0, B2y = 0, B3x = 0, B3y = 0;
#define DSTEP(S, KY, BX, BY)                              \
  {                                                       \
    float2 v = Ys[(S) * 32 + kx];                         \
    float2 z = tw[(h0 * (KY)) & 255];                     \
    BX += v.x * z.x - v.y * z.y;                          \
    BY += v.x * z.y + v.y * z.x;                          \
  }
#pragma unroll 4
      for (int sb = 0; sb < 32; sb += 4) {
        DSTEP(sb + 0, sb + 0, B0x, B0y);
        DSTEP(sb + 1, sb + 1, B1x, B1y);
        DSTEP(sb + 2, sb + 2, B2x, B2y);
        DSTEP(sb + 3, sb + 3, B3x, B3y);
      }
#pragma unroll 4
      for (int sb = 32; sb < 64; sb += 4) {
        DSTEP(sb + 0, sb + 192, B0x, B0y);
        DSTEP(sb + 1, sb + 193, B1x, B1y);
        DSTEP(sb + 2, sb + 194, B2x, B2y);
        DSTEP(sb + 3, sb + 195, B3x, B3y);
      }
#undef DSTEP
      const float Ex = B0x + B2x, Ey = B0y + B2y, Fx = B1x + B3x, Fy = B1y + B3y;
      const float Gx = B0x - B2x, Gy = B0y - B2y, Hx = B1x - B3x, Hy = B1y - B3y;
      float2* yb = &Y1c[(h0 - h0base) * 32 + kx];
      yb[0]    = make_float2((Ex + Fx) * scale, (Ey + Fy) * scale);
      yb[1024] = make_float2((Gx - Hy) * scale, (Gy + Hx) * scale);
      yb[2048] = make_float2((Ex - Fx) * scale, (Ey - Fy) * scale);
      yb[3072] = make_float2((Gx + Hy) * scale, (Gy - Hx) * scale);
    }
    __syncthreads();
    // ---- Stage E: wave wv owns quadrant q=wv ----
    for (int j = 0; j < 32; ++j) {
      const float2* row = &Y1c[wv * 1024 + j * 32];
      float p0 = 0, p2 = 0, P1x = 0, P1y = 0, P3x = 0, P3y = 0;
#pragma unroll
      for (int kb = 0; kb < 32; kb += 4) {
        float4 v01 = *(const float4*)(row + kb);
        float4 v23 = *(const float4*)(row + kb + 2);
        p0  += v01.x * T[kb].x     - v01.y * T[kb].y;
        P1x += v01.z * T[kb + 1].x - v01.w * T[kb + 1].y;
        P1y += v01.z * T[kb + 1].y + v01.w * T[kb + 1].x;
        p2  += v23.x * T[kb + 2].x - v23.y * T[kb + 2].y;
        P3x += v23.z * T[kb + 3].x - v23.w * T[kb + 3].y;
        P3y += v23.z * T[kb + 3].y + v23.w * T[kb + 3].x;
      }
      const int h = wv * 64 + h0base + j;
      float* o = op + h * 256 + lane;
      o[0]   = p0 + P1x + p2 + P3x;
      o[64]  = p0 - P1y - p2 + P3y;
      o[128] = p0 - P1x + p2 - P3x;
      o[192] = p0 + P1y - p2 - P3y;
    }
    __syncthreads();  // before next pass overwrites Y1c
  }
}

extern "C" void kernel_launch(void* const* d_in, const int* in_sizes, int n_in,
                              void* d_out, int out_size, void* d_ws, size_t ws_size,
                              hipStream_t stream) {
  const float* x = (const float*)d_in[0];
  const float* w1re = (const float*)d_in[1];
  const float* w1im = (const float*)d_in[2];
  const float* w4re = (const float*)d_in[3];
  const float* w4im = (const float*)d_in[4];
  float* out = (float*)d_out;
  float2* X2 = (float2*)d_ws;                 // 16 MB
  float2* Y2 = X2 + (size_t)1024 * 2048;      // 16 MB

  fwd_dft<<<1024, 256, 0, stream>>>(x, X2);
  mix<<<2048, 256, 0, stream>>>(X2, w1re, w1im, w4re, w4im, Y2);
  inv_dft<<<1024, 256, 0, stream>>>(Y2, out);
}

// Round 2
// 820.800 us; speedup vs baseline: 1.6534x; 1.6534x over previous
//
#include <hip/hip_runtime.h>

// x (P,B,C,H,W)=(8,4,32,256,256) fp32; w* (C,C,P,M1,M2)=(32,32,8,32,32)
// Kept modes: ky in [0,32) u [224,256)  (s=0..63, ky = s<32 ? s : s+192), kx in [0,32)

constexpr float TWO_PI = 6.28318530717958647692f;

// ---------------- Kernel 1: forward truncated DFT per plane ----------------
// Single-pass restructure (both kx halves at once):
//   Chunk-pair c (c<16): rows h = c*8+r and h+128 (r<8) are loaded and
//   w-parity-folded into u[par][row16][w00*8+w1]  (w0 = 16*w1 + w00).
//   Stage A: thread (row16, kxh) computes X1[row][kx] for BOTH kx=kxh and
//   kxh+16 (inner sums shared; only the A[w00] twiddles differ, LDS table).
//   Stage B: thread (sg, kx) holds 8 output modes s=sg+8j (constant parity)
//   in registers, accumulates per chunk from buf, folding h-parity on the fly.
//   Global loads for c+1 issued before stage A, written to LDS after stage B.
// NOTE: no min-occupancy in __launch_bounds__ — round-1's (256,4) clamped
// VGPR to 64 and spilled 2.3 GB of scratch traffic (FETCH 262MB->1.08GB).
__global__ __launch_bounds__(256) void fwd_dft(const float* __restrict__ x,
                                               float2* __restrict__ X2) {
  __shared__ float2 tw[256];                       // e^{+2pi i t/256}
  __shared__ float2 At[512];                       // [w00][kx]: e^{-2pi i w00 kx/256}
  __shared__ __align__(16) float u[2 * 16 * 132];  // [par][row16][w00*8+w1]
  __shared__ float2 buf[16 * 33];                  // X1 chunk [row16][kx], stride 33

  const int t = threadIdx.x;
  {
    float a = (float)t * (TWO_PI / 256.f);
    tw[t] = make_float2(cosf(a), sinf(a));
  }
#pragma unroll
  for (int i = 0; i < 2; ++i) {
    int idx = t + 256 * i;
    int w00 = idx >> 5, kx = idx & 31;
    float a = (TWO_PI / 256.f) * (float)(w00 * kx);
    At[idx] = make_float2(cosf(a), -sinf(a));
  }

  // stage A role
  const int rowA = t >> 4, kxh = t & 15, par = kxh & 1;
  float2 Bt[8];
#pragma unroll
  for (int w1 = 0; w1 < 8; ++w1) {
    float a = (TWO_PI / 16.f) * (float)(w1 * kxh);
    Bt[w1] = make_float2(cosf(a), -sinf(a));
  }
  // loader role
  const int lrow = t >> 5, w4 = t & 31;
  const float4* x4 = (const float4*)(x + (size_t)blockIdx.x * 65536);
  // stage B role (kxb == w4, sg == lrow; kept separate for clarity)
  const int sg = t >> 5, kxb = t & 31;
  const float sgn = (sg & 1) ? -1.f : 1.f;
  float2 acc[8];
#pragma unroll
  for (int j = 0; j < 8; ++j) acc[j] = make_float2(0.f, 0.f);

  float* const U0 = u;
  float* const U1 = u + 2112;
  const int ibase = lrow * 132 + 32 * (w4 & 3) + (w4 >> 2);
  const float* const up = u + par * 2112 + rowA * 132;

  float4 pa0, pb0, pa1, pb1;

#define LOADC(c)                        \
  {                                     \
    int h = (c) * 8 + lrow;             \
    pa0 = x4[h * 64 + w4];              \
    pb0 = x4[h * 64 + w4 + 32];         \
    pa1 = x4[(h + 128) * 64 + w4];      \
    pb1 = x4[(h + 128) * 64 + w4 + 32]; \
  }
#define STOREU()                                                      \
  {                                                                   \
    U0[ibase] = pa0.x + pb0.x;      U1[ibase] = pa0.x - pb0.x;        \
    U0[ibase + 8] = pa0.y + pb0.y;  U1[ibase + 8] = pa0.y - pb0.y;    \
    U0[ibase + 16] = pa0.z + pb0.z; U1[ibase + 16] = pa0.z - pb0.z;   \
    U0[ibase + 24] = pa0.w + pb0.w; U1[ibase + 24] = pa0.w - pb0.w;   \
    const int i1 = ibase + 1056;                                      \
    U0[i1] = pa1.x + pb1.x;      U1[i1] = pa1.x - pb1.x;              \
    U0[i1 + 8] = pa1.y + pb1.y;  U1[i1 + 8] = pa1.y - pb1.y;          \
    U0[i1 + 16] = pa1.z + pb1.z; U1[i1 + 16] = pa1.z - pb1.z;         \
    U0[i1 + 24] = pa1.w + pb1.w; U1[i1 + 24] = pa1.w - pb1.w;         \
  }

  LOADC(0);
  STOREU();
  __syncthreads();

#pragma unroll 1
  for (int c = 0; c < 16; ++c) {
    if (c < 15) LOADC(c + 1);  // issue early; consumed by STOREU after stage B
    // ---- stage A: X1 for 16 rows x 32 kx of this chunk-pair ----
    float ax1 = 0.f, ay1 = 0.f, ax2 = 0.f, ay2 = 0.f;
#pragma unroll
    for (int w00 = 0; w00 < 16; ++w00) {
      float4 q0 = *(const float4*)(up + w00 * 8);
      float4 q1 = *(const float4*)(up + w00 * 8 + 4);
      float Sx = q0.x + q0.y * Bt[1].x + q0.z * Bt[2].x + q0.w * Bt[3].x +
                 q1.x * Bt[4].x + q1.y * Bt[5].x + q1.z * Bt[6].x +
                 q1.w * Bt[7].x;
      float Sy = q0.y * Bt[1].y + q0.z * Bt[2].y + q0.w * Bt[3].y +
                 q1.x * Bt[4].y + q1.y * Bt[5].y + q1.z * Bt[6].y +
                 q1.w * Bt[7].y;
      float2 A1 = At[w00 * 32 + kxh];
      float2 A2 = At[w00 * 32 + kxh + 16];
      ax1 += A1.x * Sx - A1.y * Sy;
      ay1 += A1.x * Sy + A1.y * Sx;
      ax2 += A2.x * Sx - A2.y * Sy;
      ay2 += A2.x * Sy + A2.y * Sx;
    }
    buf[rowA * 33 + kxh] = make_float2(ax1, ay1);
    buf[rowA * 33 + kxh + 16] = make_float2(ax2, ay2);
    __syncthreads();
    // ---- stage B: fold h-parity, accumulate 8 modes per thread ----
#pragma unroll
    for (int r = 0; r < 8; ++r) {
      const int h0 = c * 8 + r;
      float2 a = buf[r * 33 + kxb];
      float2 b = buf[(r + 8) * 33 + kxb];
      float vx = fmaf(sgn, b.x, a.x);
      float vy = fmaf(sgn, b.y, a.y);
      int tix = h0 * sg;        // (h0*ky_j)&255 walked incrementally
      const int h8 = h0 << 3;
#pragma unroll
      for (int j = 0; j < 8; ++j) {
        float2 z = tw[tix & 255];
        // acc += v * conj(z)
        acc[j].x += vx * z.x + vy * z.y;
        acc[j].y += vy * z.x - vx * z.y;
        tix += h8;
        if (j == 3) tix += (h0 << 7) + (h0 << 6);  // jump ky by +192 at s>=32
      }
    }
    if (c < 15) STOREU();
    __syncthreads();
  }
#undef LOADC
#undef STOREU

  float2* X2p = X2 + (size_t)blockIdx.x * 2048;
#pragma unroll
  for (int j = 0; j < 8; ++j) X2p[(sg + 8 * j) * 32 + kxb] = acc[j];
}

// ---------------- Kernel 2: channel mixing (unchanged) ----------------
__global__ __launch_bounds__(256) void mix(const float2* __restrict__ X2,
                                           const float* __restrict__ w1re,
                                           const float* __restrict__ w1im,
                                           const float* __restrict__ w4re,
                                           const float* __restrict__ w4im,
                                           float2* __restrict__ Y2) {
  const int n = blockIdx.x * 256 + threadIdx.x;
  const int kx = n & 31;
  const int s = (n >> 5) & 63;
  const int o = (n >> 11) & 31;
  const int p = n >> 16;
  const float* wre;
  const float* wim;
  int y;
  if (s < 32) { wre = w1re; wim = w1im; y = s; }
  else        { wre = w4re; wim = w4im; y = s - 32; }
  const size_t wbase = (size_t)o * 8192 + (size_t)p * 1024 + y * 32 + kx;
  const size_t in_base = ((size_t)p * 4 * 32) * 2048 + s * 32 + kx;
  float2 acc[4] = {make_float2(0.f, 0.f), make_float2(0.f, 0.f),
                   make_float2(0.f, 0.f), make_float2(0.f, 0.f)};
#pragma unroll 4
  for (int i = 0; i < 32; ++i) {
    const float wr = wre[wbase + (size_t)i * 262144];
    const float wi = wim[wbase + (size_t)i * 262144];
#pragma unroll
    for (int b = 0; b < 4; ++b) {
      float2 v = X2[in_base + (size_t)b * 65536 + (size_t)i * 2048];
      acc[b].x += v.x * wr - v.y * wi;
      acc[b].y += v.x * wi + v.y * wr;
    }
  }
  const size_t out_base = ((size_t)p * 4 * 32 + o) * 2048 + s * 32 + kx;
#pragma unroll
  for (int b = 0; b < 4; ++b) Y2[out_base + (size_t)b * 65536] = acc[b];
}

// ---------------- Kernel 3: inverse truncated DFT per plane ----------------
__global__ __launch_bounds__(256) void inv_dft(const float2* __restrict__ Y2,
                                               float* __restrict__ out) {
  __shared__ float2 tw[256];
  __shared__ float2 Ys[64 * 32];       // input modes [s][kx]
  __shared__ float2 Y1c[4 * 32 * 32];  // [q][hh][k] compact quad rows
  const int t = threadIdx.x;
  {
    float a = (float)t * (TWO_PI / 256.f);
    tw[t] = make_float2(cosf(a), sinf(a));
  }
  {
    const float4* src = (const float4*)(Y2 + (size_t)blockIdx.x * 2048);
    float4* dst = (float4*)Ys;
#pragma unroll
    for (int q = 0; q < 4; ++q) dst[t + 256 * q] = src[t + 256 * q];
  }
  const int lane = t & 63, wv = t >> 6;
  const int kx = lane & 31, hg = lane >> 5;
  const float scale = (kx == 0) ? (1.f / 65536.f) : (2.f / 65536.f);
  // Stage E register twiddles: T[k] = e^{+2pi i lane*k/256}
  float2 T[32];
#pragma unroll
  for (int k = 0; k < 32; ++k) {
    float a = (TWO_PI / 256.f) * (float)(lane * k);
    T[k] = make_float2(cosf(a), sinf(a));
  }
  __syncthreads();
  float* op = out + (size_t)blockIdx.x * 65536;

  for (int pass = 0; pass < 2; ++pass) {
    const int h0base = pass * 32;
    // ---- Stage D ----
    for (int iter = 0; iter < 4; ++iter) {
      const int h0 = h0base + wv * 8 + iter * 2 + hg;
      float B0x = 0, B0y = 0, B1x = 0, B1y = 0;
      float B2x = 0, B2y = 0, B3x = 0, B3y = 0;
#define DSTEP(S, KY, BX, BY)                              \
  {                                                       \
    float2 v = Ys[(S) * 32 + kx];                         \
    float2 z = tw[(h0 * (KY)) & 255];                     \
    BX += v.x * z.x - v.y * z.y;                          \
    BY += v.x * z.y + v.y * z.x;                          \
  }
#pragma unroll 4
      for (int sb = 0; sb < 32; sb += 4) {
        DSTEP(sb + 0, sb + 0, B0x, B0y);
        DSTEP(sb + 1, sb + 1, B1x, B1y);
        DSTEP(sb + 2, sb + 2, B2x, B2y);
        DSTEP(sb + 3, sb + 3, B3x, B3y);
      }
#pragma unroll 4
      for (int sb = 32; sb < 64; sb += 4) {
        DSTEP(sb + 0, sb + 192, B0x, B0y);
        DSTEP(sb + 1, sb + 193, B1x, B1y);
        DSTEP(sb + 2, sb + 194, B2x, B2y);
        DSTEP(sb + 3, sb + 195, B3x, B3y);
      }
#undef DSTEP
      const float Ex = B0x + B2x, Ey = B0y + B2y, Fx = B1x + B3x, Fy = B1y + B3y;
      const float Gx = B0x - B2x, Gy = B0y - B2y, Hx = B1x - B3x, Hy = B1y - B3y;
      float2* yb = &Y1c[(h0 - h0base) * 32 + kx];
      yb[0]    = make_float2((Ex + Fx) * scale, (Ey + Fy) * scale);
      yb[1024] = make_float2((Gx - Hy) * scale, (Gy + Hx) * scale);
      yb[2048] = make_float2((Ex - Fx) * scale, (Ey - Fy) * scale);
      yb[3072] = make_float2((Gx + Hy) * scale, (Gy - Hx) * scale);
    }
    __syncthreads();
    // ---- Stage E: wave wv owns quadrant q=wv ----
    for (int j = 0; j < 32; ++j) {
      const float2* row = &Y1c[wv * 1024 + j * 32];
      float p0 = 0, p2 = 0, P1x = 0, P1y = 0, P3x = 0, P3y = 0;
#pragma unroll
      for (int kb = 0; kb < 32; kb += 4) {
        float4 v01 = *(const float4*)(row + kb);
        float4 v23 = *(const float4*)(row + kb + 2);
        p0  += v01.x * T[kb].x     - v01.y * T[kb].y;
        P1x += v01.z * T[kb + 1].x - v01.w * T[kb + 1].y;
        P1y += v01.z * T[kb + 1].y + v01.w * T[kb + 1].x;
        p2  += v23.x * T[kb + 2].x - v23.y * T[kb + 2].y;
        P3x += v23.z * T[kb + 3].x - v23.w * T[kb + 3].y;
        P3y += v23.z * T[kb + 3].y + v23.w * T[kb + 3].x;
      }
      const int h = wv * 64 + h0base + j;
      float* o = op + h * 256 + lane;
      o[0]   = p0 + P1x + p2 + P3x;
      o[64]  = p0 - P1y - p2 + P3y;
      o[128] = p0 - P1x + p2 - P3x;
      o[192] = p0 + P1y - p2 - P3y;
    }
    __syncthreads();  // before next pass overwrites Y1c
  }
}

extern "C" void kernel_launch(void* const* d_in, const int* in_sizes, int n_in,
                              void* d_out, int out_size, void* d_ws, size_t ws_size,
                              hipStream_t stream) {
  const float* x = (const float*)d_in[0];
  const float* w1re = (const float*)d_in[1];
  const float* w1im = (const float*)d_in[2];
  const float* w4re = (const float*)d_in[3];
  const float* w4im = (const float*)d_in[4];
  float* out = (float*)d_out;
  float2* X2 = (float2*)d_ws;                 // 16 MB
  float2* Y2 = X2 + (size_t)1024 * 2048;      // 16 MB

  fwd_dft<<<1024, 256, 0, stream>>>(x, X2);
  mix<<<2048, 256, 0, stream>>>(X2, w1re, w1im, w4re, w4im, Y2);
  inv_dft<<<1024, 256, 0, stream>>>(Y2, out);
}